// Round 18
// baseline (30.676 us; speedup 1.0000x reference)
//
#include <hip/hip_runtime.h>
#include <hip/hip_bf16.h>

#define N_PTS 4096
#define D_EMB 64
#define NPART 1024                                 // one partial-set per block

typedef __attribute__((ext_vector_type(8))) short bf16x8;  // 8 bf16 = 4 VGPR
typedef __attribute__((ext_vector_type(4))) float f32x4;   // MFMA 16x16 acc

// ---------------------------------------------------------------------------
// Prep (unchanged, verified): fragment-major bf16 hi/lo split + exact norms.
// ---------------------------------------------------------------------------
__global__ void prep_kernel(const float* __restrict__ mapping,
                            ushort* __restrict__ MhiT,
                            ushort* __restrict__ MloT,
                            float* __restrict__ nrm) {
  const int g = blockIdx.x;           // 16-row group 0..255
  const int l = threadIdx.x;          // 0..63
  const int r16 = l & 15, kg = l >> 4;
  float s = 0.f;
  #pragma unroll
  for (int ks = 0; ks < 2; ++ks) {
    bf16x8 vh, vl;
    #pragma unroll
    for (int j = 0; j < 8; ++j) {
      const int col = ks * 32 + kg * 8 + j;
      const float x = mapping[(g * 16 + r16) * D_EMB + col];
      s = fmaf(x, x, s);
      __hip_bfloat16 h = __float2bfloat16(x);
      const float hf = __bfloat162float(h);
      __hip_bfloat16 lo = __float2bfloat16(x - hf);
      vh[j] = (short)*reinterpret_cast<ushort*>(&h);
      vl[j] = (short)*reinterpret_cast<ushort*>(&lo);
    }
    const size_t base = ((size_t)(g * 2 + ks) * 64 + l) * 8;
    *(bf16x8*)(MhiT + base) = vh;
    *(bf16x8*)(MloT + base) = vl;
  }
  s += __shfl_xor(s, 16);
  s += __shfl_xor(s, 32);
  if (kg == 0) nrm[g * 16 + r16] = s;
}

// ---------------------------------------------------------------------------
// R17 (bL dropped; 30.3us) + R16's D/rB register double-buffer prefetch.
//   dot = Hj.Hi + Hj.Li   (Lj.Hi and Lj.Li dropped; absmax 0.0 in R17)
//
// Rationale (R15 probes + R16/R17 post-mortems): critical path = D-stream
// floor (~11us, delivered-BW roofline) + ~7.6us EXPOSED epilogue latency.
// R16's prefetch failed only because +20 VGPR pushed 110->130 -> 3
// waves/SIMD. R17's bL-drop freed 16 VGPR but alone changed nothing (off
// the critical path). COMBO: bL-drop pays the VGPR bill for the prefetch;
// net ~114 VGPR keeps 4 waves/SIMD AND the epilogue runs with the next
// tile's D already in flight (vmcnt allows the 13 newer loads to stay
// outstanding while epilogue consumes D4[cur]).
// Pre-commit: >=30us total -> declare roofline.
// ---------------------------------------------------------------------------
__global__ __launch_bounds__(256) void distortion_main(
    const ushort* __restrict__ MhiT, const ushort* __restrict__ MloT,
    const float* __restrict__ Dm, const float* __restrict__ nrm,
    double* __restrict__ part) {
  __shared__ __align__(16) float sg[4][1024];   // wave-private 32x32 f32
  __shared__ float redv[16];                    // 4 waves x 4 sums

  const int t = threadIdx.x;
  const int w = t >> 6, l = t & 63;
  const int r16 = l & 15, kg = l >> 4;
  const int wr = w >> 1, wc = w & 1;
  const int I  = blockIdx.y * 64 + wr * 32;     // wave rows I..I+31
  const int Jb = blockIdx.x * 256 + wc * 32;    // wave col base; +jt*64
  const int jc8 = l & 7, is8 = l >> 3;

  // ---- per-wave constants: a-fragments + row norms (loaded ONCE)
  bf16x8 aH[2][2], aL[2][2];                    // [ks][m]
  #pragma unroll
  for (int ks = 0; ks < 2; ++ks)
    #pragma unroll
    for (int m = 0; m < 2; ++m) {
      const size_t fa = (((size_t)((I >> 4) + m) * 2 + ks) * 64 + l) * 8;
      aH[ks][m] = *(const bf16x8*)(MhiT + fa);
      aL[ks][m] = *(const bf16x8*)(MloT + fa);
    }
  float rA[4];
  #pragma unroll
  for (int it = 0; it < 4; ++it) rA[it] = nrm[I + it * 8 + is8];

  float* sgw = sg[w];
  float s1 = 0.f, s2 = 0.f, s3 = 0.f, s4 = 0.f;

  // ---- D/rB register double-buffer; preload tile 0
  float4 D4[2][4];
  float4 rB4[2];
  #pragma unroll
  for (int it = 0; it < 4; ++it)
    D4[0][it] = *(const float4*)(Dm + (size_t)(I + it * 8 + is8) * N_PTS +
                                 Jb + jc8 * 4);
  rB4[0] = *(const float4*)(nrm + Jb + jc8 * 4);

  #pragma unroll
  for (int jt = 0; jt < 4; ++jt) {
    const int cur = jt & 1, nxt = cur ^ 1;      // compile-time after unroll
    const int J = Jb + jt * 64;

    // ---- issue b-frag loads for THIS tile (bH only; bL dropped)
    bf16x8 bH[2][2];
    #pragma unroll
    for (int ks = 0; ks < 2; ++ks)
      #pragma unroll
      for (int n = 0; n < 2; ++n) {
        const size_t fb = (((size_t)((J >> 4) + n) * 2 + ks) * 64 + l) * 8;
        bH[ks][n] = *(const bf16x8*)(MhiT + fb);
      }

    // ---- issue D/rB prefetch for NEXT tile (the long-pole stream)
    if (jt < 3) {
      const int Jn = J + 64;
      #pragma unroll
      for (int it = 0; it < 4; ++it)
        D4[nxt][it] = *(const float4*)(Dm + (size_t)(I + it * 8 + is8) * N_PTS +
                                       Jn + jc8 * 4);
      rB4[nxt] = *(const float4*)(nrm + Jn + jc8 * 4);
    }

    // ---- MFMA (swapped operands; layout HW-verified)
    f32x4 acc[2][2] = {};
    #pragma unroll
    for (int ks = 0; ks < 2; ++ks)
      #pragma unroll
      for (int m = 0; m < 2; ++m)
        #pragma unroll
        for (int n = 0; n < 2; ++n) {
          acc[m][n] = __builtin_amdgcn_mfma_f32_16x16x32_bf16(
              bH[ks][n], aH[ks][m], acc[m][n], 0, 0, 0);   // Hj.Hi
          acc[m][n] = __builtin_amdgcn_mfma_f32_16x16x32_bf16(
              bH[ks][n], aL[ks][m], acc[m][n], 0, 0, 0);   // Hj.Li
        }

    // ---- wave-private transpose (no barrier; in-order DS within wave)
    #pragma unroll
    for (int m = 0; m < 2; ++m) {
      const int i_loc = m * 16 + r16;
      #pragma unroll
      for (int n = 0; n < 2; ++n) {
        const int jc4 = n * 4 + kg;
        *(f32x4*)(sgw + i_loc * 32 + ((jc4 ^ (i_loc & 7)) << 2)) = acc[m][n];
      }
    }

    // ---- epilogue for THIS tile; next tile's D/rB already in flight
    #pragma unroll
    for (int it = 0; it < 4; ++it) {
      const int i_loc = it * 8 + is8;
      const int gi = I + i_loc;
      const f32x4 g4 =
          *(const f32x4*)(sgw + i_loc * 32 + ((jc8 ^ (i_loc & 7)) << 2));
      const float4 Dv4 = D4[cur][it];
      const float4 rBt = rB4[cur];
      #pragma unroll
      for (int r = 0; r < 4; ++r) {
        const float Dv  = (r == 0) ? Dv4.x : (r == 1) ? Dv4.y : (r == 2) ? Dv4.z : Dv4.w;
        const float rB  = (r == 0) ? rBt.x : (r == 1) ? rBt.y : (r == 2) ? rBt.z : rBt.w;
        const float dot = g4[r];
        const float sq = fmaxf(rA[it] + rB - 2.f * dot, 0.f);
        float dd = __builtin_amdgcn_sqrtf(sq);
        const bool diag = (gi == J + jc8 * 4 + r);
        if (diag) dd = 0.f;                      // exact: ||x-x|| = 0
        const float denom = Dv + (diag ? 1.f : 0.f) + 1e-8f;
        const float rd = __builtin_amdgcn_rcpf(denom);
        const float av = dd * rd;                // a = d/denom
        const float bv = Dv * rd;                // b = D/denom
        s1 += av;
        s2 = fmaf(av, av, s2);
        s3 = fmaf(av, bv, s3);
        s4 = fmaf(bv, bv, s4);
      }
    }
  }

  // ---- one reduce per wave, block reduce, one write-set per block
  #pragma unroll
  for (int off = 32; off > 0; off >>= 1) {
    s1 += __shfl_down(s1, off);
    s2 += __shfl_down(s2, off);
    s3 += __shfl_down(s3, off);
    s4 += __shfl_down(s4, off);
  }
  if (l == 0) {
    redv[w * 4 + 0] = s1; redv[w * 4 + 1] = s2;
    redv[w * 4 + 2] = s3; redv[w * 4 + 3] = s4;
  }
  __syncthreads();
  if (t < 4) {
    const double v = (double)redv[0 * 4 + t] + (double)redv[1 * 4 + t] +
                     (double)redv[2 * 4 + t] + (double)redv[3 * 4 + t];
    const int bid = blockIdx.y * gridDim.x + blockIdx.x;
    part[t * NPART + bid] = v;
  }
}

// ---------------------------------------------------------------------------
// Reduce 4 x 1024 partials; emit s^2*S2 - 2 s S3 + S4, s = S1/S2.
// ---------------------------------------------------------------------------
__global__ __launch_bounds__(1024) void distortion_final(
    const double* __restrict__ part, float* __restrict__ out) {
  __shared__ double red[16][4];
  const int t = threadIdx.x;
  double s[4];
  #pragma unroll
  for (int k = 0; k < 4; ++k) s[k] = part[k * NPART + t];
  #pragma unroll
  for (int off = 32; off > 0; off >>= 1)
    #pragma unroll
    for (int k = 0; k < 4; ++k) s[k] += __shfl_down(s[k], off);
  const int w = t >> 6, l = t & 63;
  if (l == 0) {
    #pragma unroll
    for (int k = 0; k < 4; ++k) red[w][k] = s[k];
  }
  __syncthreads();
  if (t == 0) {
    double S0 = 0, S1 = 0, S2 = 0, S3 = 0;
    #pragma unroll
    for (int ww = 0; ww < 16; ++ww) {
      S0 += red[ww][0]; S1 += red[ww][1]; S2 += red[ww][2]; S3 += red[ww][3];
    }
    const double sc = S0 / S1;
    const double r = (sc * sc * S1 - 2.0 * sc * S2 + S3) /
                     ((double)N_PTS * (double)N_PTS - (double)N_PTS);
    out[0] = (float)r;
  }
}

extern "C" void kernel_launch(void* const* d_in, const int* in_sizes, int n_in,
                              void* d_out, int out_size, void* d_ws, size_t ws_size,
                              hipStream_t stream) {
  const float* mapping = (const float*)d_in[0];
  const float* Dm = (const float*)d_in[1];
  float* out = (float*)d_out;
  // ws layout: nrm 16KB | part 32KB | MhiT 512KB | MloT 512KB (~1.07 MB)
  float* nrm = (float*)d_ws;
  double* part = (double*)((char*)d_ws + 16384);
  ushort* MhiT = (ushort*)((char*)d_ws + 16384 + 32768);
  ushort* MloT = (ushort*)((char*)d_ws + 16384 + 32768 + 524288);

  prep_kernel<<<dim3(N_PTS / 16), dim3(64), 0, stream>>>(mapping, MhiT, MloT, nrm);
  distortion_main<<<dim3(16, 64), dim3(256), 0, stream>>>(MhiT, MloT, Dm, nrm, part);
  distortion_final<<<1, 1024, 0, stream>>>(part, out);
}